// Round 9
// baseline (86.186 us; speedup 1.0000x reference)
//
#include <hip/hip_runtime.h>
#include <stdint.h>

// Problem constants
#define CHELEM 131072        // 2048*64 elements per chunk (flat-reshape chunk)

typedef __attribute__((ext_vector_type(4))) float   f32x4;
typedef __attribute__((ext_vector_type(8))) short   bh8;     // 8 bf16 in 4 VGPRs
typedef __attribute__((ext_vector_type(4))) unsigned short u16x4;
typedef __attribute__((ext_vector_type(8))) unsigned short u16x8;
typedef unsigned short u16;

__device__ inline u16 f2bf(float f) {
    union { float f; uint32_t u; } v; v.f = f;
    uint32_t u = v.u;
    u += 0x7FFF + ((u >> 16) & 1);         // RNE
    return (u16)(u >> 16);
}

__device__ inline void gload_lds16(const u16* g, u16* l) {
    __builtin_amdgcn_global_load_lds(
        (const __attribute__((address_space(1))) uint32_t*)g,
        (__attribute__((address_space(3)))       uint32_t*)l,
        16, 0, 0);
}

// ---------------- K0: convert x, Wq, Wk, Wv to bf16 (+ reset flag) ----------------
__global__ __launch_bounds__(256) void k0_convert(
        const float* __restrict__ x,
        const float* __restrict__ Wq,
        const float* __restrict__ Wk,
        const float* __restrict__ Wv,
        u16* __restrict__ xb, u16* __restrict__ Wb,
        int* __restrict__ flag) {
    if (blockIdx.x == 0 && threadIdx.x == 0)
        __hip_atomic_store(flag, 0, __ATOMIC_RELAXED, __HIP_MEMORY_SCOPE_AGENT);
    int idx = blockIdx.x * 256 + threadIdx.x;   // float4 index, 720896 total
    const float4* src; u16* dst; int off;
    if (idx < 524288) { src = (const float4*)x; dst = xb; off = idx; }
    else {
        int j = idx - 524288;
        int w = j >> 16;                        // 65536 float4 per W
        off = j & 65535;
        src = (const float4*)(w == 0 ? Wq : (w == 1 ? Wk : Wv));
        dst = Wb + w * 262144;
    }
    float4 f = src[off];
    u16x4 o;
    o[0] = f2bf(f.x); o[1] = f2bf(f.y); o[2] = f2bf(f.z); o[3] = f2bf(f.w);
    *(u16x4*)(dst + off * 4) = o;
}

// ---------------- K1: QKV projection GEMM (verbatim R8 winner) ----------------
// C[m,n] = sum_k xb[m,k]*W[n,k] + bias[n]  (gemm_bt), 64x128 tile, 768 blocks.
// Q (w==0): straight [4096][512]. K,V: TRANSPOSED per chunk Kt2[c][d][g][q]
// (c=m>>8, d=f&63, g=f>>6, q=m&255; row r=q*8+g bijection, same perm for K,V).
__global__ __launch_bounds__(256) void k1_qkv(
        const u16* __restrict__ xb, const u16* __restrict__ Wb,
        const float* __restrict__ bq, const float* __restrict__ bk,
        const float* __restrict__ bv,
        u16* __restrict__ Qb, u16* __restrict__ Kb, u16* __restrict__ Vb) {
    __shared__ u16 smem[12288];                 // lA[4096]+lB[8192]; epi tile[64][130] aliases
    u16* lA = smem;
    u16* lB = smem + 4096;
    const int tid  = threadIdx.x;
    const int lane = tid & 63, wid = tid >> 6;
    const int wr = wid >> 1, wc = wid & 1;
    const int swz  = (blockIdx.x & 7) * 96 + (blockIdx.x >> 3);   // XCD swizzle
    const int mb = swz / 12, nb = swz % 12;
    const int w    = nb >> 2;
    const int nloc = (nb & 3) * 128;
    const u16*   W    = Wb + w * 262144;
    const float* bias = (w == 0) ? bq : ((w == 1) ? bk : bv);
    u16*         out  = (w == 0) ? Qb : ((w == 1) ? Kb : Vb);
    const int m0 = mb * 64;

    f32x4 acc[2][4] = {};
    const int srow = tid >> 3;
    const int scol = (tid & 7) * 8;

    for (int kb = 0; kb < 8; ++kb) {
        __syncthreads();
        const int k0 = kb * 64;
#pragma unroll
        for (int it = 0; it < 2; ++it) {
            int r = it * 32 + srow;
            gload_lds16(xb + (size_t)(m0 + r) * 512 + k0 + scol, lA + r * 64 + scol);
        }
#pragma unroll
        for (int it = 0; it < 4; ++it) {
            int r = it * 32 + srow;
            gload_lds16(W + (size_t)(nloc + r) * 512 + k0 + scol, lB + r * 64 + scol);
        }
        asm volatile("s_waitcnt vmcnt(0)" ::: "memory");
        __syncthreads();
#pragma unroll
        for (int ks = 0; ks < 2; ++ks) {
            const int kk = ks * 32 + (lane >> 4) * 8;
            bh8 a[2], b[4];
#pragma unroll
            for (int i = 0; i < 2; ++i)
                a[i] = *(const bh8*)&lA[(wr * 32 + i * 16 + (lane & 15)) * 64 + kk];
#pragma unroll
            for (int j = 0; j < 4; ++j)
                b[j] = *(const bh8*)&lB[(wc * 64 + j * 16 + (lane & 15)) * 64 + kk];
#pragma unroll
            for (int i = 0; i < 2; ++i)
#pragma unroll
                for (int j = 0; j < 4; ++j)
                    acc[i][j] = __builtin_amdgcn_mfma_f32_16x16x32_bf16(a[i], b[j], acc[i][j], 0, 0, 0);
        }
    }

    if (w == 0) {
#pragma unroll
        for (int i = 0; i < 2; ++i) {
            const int row_base = m0 + wr * 32 + i * 16 + ((lane >> 4) * 4);
#pragma unroll
            for (int j = 0; j < 4; ++j) {
                const int col = nloc + wc * 64 + j * 16 + (lane & 15);
                const float bv_ = bias[col];
#pragma unroll
                for (int r = 0; r < 4; ++r)
                    out[(size_t)(row_base + r) * 512 + col] = f2bf(acc[i][j][r] + bv_);
            }
        }
    } else {
        __syncthreads();
        u16 (*tile)[130] = (u16(*)[130])smem;
#pragma unroll
        for (int i = 0; i < 2; ++i) {
            const int ml = wr * 32 + i * 16 + ((lane >> 4) * 4);
#pragma unroll
            for (int j = 0; j < 4; ++j) {
                const int nl = wc * 64 + j * 16 + (lane & 15);
                const float bv_ = bias[nloc + nl];
#pragma unroll
                for (int r = 0; r < 4; ++r)
                    tile[ml + r][nl] = f2bf(acc[i][j][r] + bv_);
            }
        }
        __syncthreads();
        const int ncol  = tid & 127;
        const int mhalf = tid >> 7;
        const int g = (nb & 3) * 2 + (ncol >> 6);
        const int d = ncol & 63;
        const int c = mb >> 2;
        const int qbase = (mb & 3) * 64 + mhalf * 32;
        u16* dst = out + (size_t)c * CHELEM + d * 2048 + g * 256 + qbase;
#pragma unroll
        for (int v = 0; v < 4; ++v) {
            u16x8 t;
#pragma unroll
            for (int j = 0; j < 8; ++j)
                t[j] = tile[mhalf * 32 + v * 8 + j][ncol];
            *(u16x8*)(dst + v * 8) = t;
        }
    }
}

// ---------------- K23: P producers (bid<16) + Y consumers (all 128 blocks) ----------------
// Producer body = R4-verified k2_pmat (split-K direct-global, LDS reduce).
// Consumer body = R8-verified k3_out. Hand-off: device-scope release/acquire
// on flag; all 128 blocks co-resident (<=256 CUs) so no scheduling starvation.
__global__ __launch_bounds__(256) void k23_pv(
        const u16* __restrict__ Kt2, const u16* __restrict__ Vt2,
        const u16* __restrict__ Qb, u16* __restrict__ Pb,
        int* __restrict__ flag, float* __restrict__ outp) {
    __shared__ float red[4][4096];             // 64 KB (producer phase only)
    const int tid = threadIdx.x;
    const int lane = tid & 63, w = tid >> 6;
    const int bid = blockIdx.x;

    if (bid < 16) {
        // ---- produce P_c for chunk c = bid ----
        const int c = bid;
        const u16* Ac = Vt2 + (size_t)c * CHELEM;  // A = V (rows d)
        const u16* Bc = Kt2 + (size_t)c * CHELEM;  // B = K (rows e)
        f32x4 acc[4][4] = {};
        const int krow = lane & 15;
        const int kbase = w * 512 + (lane >> 4) * 8;
#pragma unroll 4
        for (int kt = 0; kt < 16; ++kt) {
            const int k0 = kbase + kt * 32;
            bh8 a[4], b[4];
#pragma unroll
            for (int i = 0; i < 4; ++i) {
                a[i] = *(const bh8*)&Ac[(i * 16 + krow) * 2048 + k0];
                b[i] = *(const bh8*)&Bc[(i * 16 + krow) * 2048 + k0];
            }
#pragma unroll
            for (int i = 0; i < 4; ++i)
#pragma unroll
                for (int j = 0; j < 4; ++j)
                    acc[i][j] = __builtin_amdgcn_mfma_f32_16x16x32_bf16(a[i], b[j], acc[i][j], 0, 0, 0);
        }
#pragma unroll
        for (int i = 0; i < 4; ++i)
#pragma unroll
            for (int j = 0; j < 4; ++j)
#pragma unroll
                for (int r = 0; r < 4; ++r)
                    red[w][(i * 16 + (lane >> 4) * 4 + r) * 64 + j * 16 + (lane & 15)] = acc[i][j][r];
        __syncthreads();
        u16* Pc = Pb + c * 4096;
#pragma unroll
        for (int q = 0; q < 16; ++q) {
            const int idx = q * 256 + tid;
            float s = red[0][idx] + red[1][idx] + red[2][idx] + red[3][idx];
            Pc[idx] = f2bf(s * 0.125f);        // scale = DIM^-0.5
        }
        __syncthreads();
        if (tid == 0) {
            __threadfence();                   // device-scope release of Pb stores
            __hip_atomic_fetch_add(flag, 1, __ATOMIC_RELEASE, __HIP_MEMORY_SCOPE_AGENT);
        }
    }

    // ---- wait for all 16 P chunks ----
    if (tid == 0) {
        int it = 0;
        while (__hip_atomic_load(flag, __ATOMIC_ACQUIRE, __HIP_MEMORY_SCOPE_AGENT) < 16) {
            __builtin_amdgcn_s_sleep(8);
            if (++it > 1000000) break;         // fail loudly (absmax), never hang
        }
    }
    __syncthreads();

    // ---- consume: out_c = Q_c @ P_c^T (R8 k3_out body) ----
    const int bb = bid >> 6;
    const int ib = bid & 63;
    const int i0 = ib * 32 + (w >> 1) * 16;
    const int dbase = (w & 1) * 32;
    const int krow = lane & 15;
    const int koff = (lane >> 4) * 8;

    f32x4 acc2[8][2] = {};
#pragma unroll
    for (int h = 0; h < 8; ++h) {
        const int c = h * 2 + bb;
        const u16* Qc = Qb + (size_t)c * CHELEM;
        const u16* Pc = Pb + c * 4096;
#pragma unroll
        for (int ks = 0; ks < 2; ++ks) {
            bh8 a = *(const bh8*)&Qc[(i0 + krow) * 64 + ks * 32 + koff];
#pragma unroll
            for (int nf = 0; nf < 2; ++nf) {
                bh8 b = *(const bh8*)&Pc[(dbase + nf * 16 + krow) * 64 + ks * 32 + koff];
                acc2[h][nf] = __builtin_amdgcn_mfma_f32_16x16x32_bf16(a, b, acc2[h][nf], 0, 0, 0);
            }
        }
    }
    const int orow_base = bb * 2048 + ib * 32 + (w >> 1) * 16 + (lane >> 4) * 4;
#pragma unroll
    for (int nf = 0; nf < 2; ++nf) {
        const int d = dbase + nf * 16 + (lane & 15);
#pragma unroll
        for (int r = 0; r < 4; ++r) {
            f32x4 lo = {acc2[0][nf][r], acc2[1][nf][r], acc2[2][nf][r], acc2[3][nf][r]};
            f32x4 hi = {acc2[4][nf][r], acc2[5][nf][r], acc2[6][nf][r], acc2[7][nf][r]};
            float* dst = outp + (size_t)(orow_base + r) * 512 + d * 8;
            *(f32x4*)dst = lo;
            *(f32x4*)(dst + 4) = hi;
        }
    }
}

extern "C" void kernel_launch(void* const* d_in, const int* in_sizes, int n_in,
                              void* d_out, int out_size, void* d_ws, size_t ws_size,
                              hipStream_t stream) {
    const float* x  = (const float*)d_in[0];
    const float* Wq = (const float*)d_in[1];
    const float* bq = (const float*)d_in[2];
    const float* Wk = (const float*)d_in[3];
    const float* bk = (const float*)d_in[4];
    const float* Wv = (const float*)d_in[5];
    const float* bv = (const float*)d_in[6];
    float* outp = (float*)d_out;

    u16* xb = (u16*)d_ws;                 // 4096*512
    u16* Wb = xb + 2097152;               // 3*512*512
    u16* Qb = Wb + 786432;                // 4096*512 (straight)
    u16* Kb = Qb + 2097152;               // Kt2 transposed chunks
    u16* Vb = Kb + 2097152;               // Vt2 transposed chunks
    u16* Pb = Vb + 2097152;               // 16*64*64
    int* flag = (int*)(Pb + 65536);

    k0_convert<<<2816, 256, 0, stream>>>(x, Wq, Wk, Wv, xb, Wb, flag);
    k1_qkv<<<768, 256, 0, stream>>>(xb, Wb, bq, bk, bv, Qb, Kb, Vb);
    k23_pv<<<128, 256, 0, stream>>>(Kb, Vb, Qb, Pb, flag, outp);
}

// Round 10
// 46.511 us; speedup vs baseline: 1.8530x; 1.8530x over previous
//
#include <hip/hip_runtime.h>
#include <stdint.h>

// Problem constants
#define CHELEM 131072        // 2048*64 elements per chunk (flat-reshape chunk)

typedef __attribute__((ext_vector_type(4))) float   f32x4;
typedef __attribute__((ext_vector_type(8))) short   bh8;     // 8 bf16 in 4 VGPRs
typedef __attribute__((ext_vector_type(4))) unsigned short u16x4;
typedef __attribute__((ext_vector_type(8))) unsigned short u16x8;
typedef unsigned short u16;

__device__ inline u16 f2bf(float f) {
    union { float f; uint32_t u; } v; v.f = f;
    uint32_t u = v.u;
    u += 0x7FFF + ((u >> 16) & 1);         // RNE
    return (u16)(u >> 16);
}

__device__ inline void gload_lds16(const u16* g, u16* l) {
    __builtin_amdgcn_global_load_lds(
        (const __attribute__((address_space(1))) uint32_t*)g,
        (__attribute__((address_space(3)))       uint32_t*)l,
        16, 0, 0);
}

// ---------------- K0: convert x, Wq, Wk, Wv to bf16 (+ reset flag) ----------------
__global__ __launch_bounds__(256) void k0_convert(
        const float* __restrict__ x,
        const float* __restrict__ Wq,
        const float* __restrict__ Wk,
        const float* __restrict__ Wv,
        u16* __restrict__ xb, u16* __restrict__ Wb,
        int* __restrict__ flag) {
    if (blockIdx.x == 0 && threadIdx.x == 0)
        __hip_atomic_store(flag, 0, __ATOMIC_RELAXED, __HIP_MEMORY_SCOPE_AGENT);
    int idx = blockIdx.x * 256 + threadIdx.x;   // float4 index, 720896 total
    const float4* src; u16* dst; int off;
    if (idx < 524288) { src = (const float4*)x; dst = xb; off = idx; }
    else {
        int j = idx - 524288;
        int w = j >> 16;                        // 65536 float4 per W
        off = j & 65535;
        src = (const float4*)(w == 0 ? Wq : (w == 1 ? Wk : Wv));
        dst = Wb + w * 262144;
    }
    float4 f = src[off];
    u16x4 o;
    o[0] = f2bf(f.x); o[1] = f2bf(f.y); o[2] = f2bf(f.z); o[3] = f2bf(f.w);
    *(u16x4*)(dst + off * 4) = o;
}

// ---------------- K1: QKV projection GEMM (verbatim R8 winner) ----------------
// C[m,n] = sum_k xb[m,k]*W[n,k] + bias[n]  (gemm_bt), 64x128 tile, 768 blocks.
// Q (w==0): straight [4096][512]. K,V: TRANSPOSED per chunk Kt2[c][d][g][q]
// (c=m>>8, d=f&63, g=f>>6, q=m&255; row r=q*8+g bijection, same perm for K,V).
__global__ __launch_bounds__(256) void k1_qkv(
        const u16* __restrict__ xb, const u16* __restrict__ Wb,
        const float* __restrict__ bq, const float* __restrict__ bk,
        const float* __restrict__ bv,
        u16* __restrict__ Qb, u16* __restrict__ Kb, u16* __restrict__ Vb) {
    __shared__ u16 smem[12288];                 // lA[4096]+lB[8192]; epi tile[64][130] aliases
    u16* lA = smem;
    u16* lB = smem + 4096;
    const int tid  = threadIdx.x;
    const int lane = tid & 63, wid = tid >> 6;
    const int wr = wid >> 1, wc = wid & 1;
    const int swz  = (blockIdx.x & 7) * 96 + (blockIdx.x >> 3);   // XCD swizzle
    const int mb = swz / 12, nb = swz % 12;
    const int w    = nb >> 2;
    const int nloc = (nb & 3) * 128;
    const u16*   W    = Wb + w * 262144;
    const float* bias = (w == 0) ? bq : ((w == 1) ? bk : bv);
    u16*         out  = (w == 0) ? Qb : ((w == 1) ? Kb : Vb);
    const int m0 = mb * 64;

    f32x4 acc[2][4] = {};
    const int srow = tid >> 3;
    const int scol = (tid & 7) * 8;

    for (int kb = 0; kb < 8; ++kb) {
        __syncthreads();
        const int k0 = kb * 64;
#pragma unroll
        for (int it = 0; it < 2; ++it) {
            int r = it * 32 + srow;
            gload_lds16(xb + (size_t)(m0 + r) * 512 + k0 + scol, lA + r * 64 + scol);
        }
#pragma unroll
        for (int it = 0; it < 4; ++it) {
            int r = it * 32 + srow;
            gload_lds16(W + (size_t)(nloc + r) * 512 + k0 + scol, lB + r * 64 + scol);
        }
        asm volatile("s_waitcnt vmcnt(0)" ::: "memory");
        __syncthreads();
#pragma unroll
        for (int ks = 0; ks < 2; ++ks) {
            const int kk = ks * 32 + (lane >> 4) * 8;
            bh8 a[2], b[4];
#pragma unroll
            for (int i = 0; i < 2; ++i)
                a[i] = *(const bh8*)&lA[(wr * 32 + i * 16 + (lane & 15)) * 64 + kk];
#pragma unroll
            for (int j = 0; j < 4; ++j)
                b[j] = *(const bh8*)&lB[(wc * 64 + j * 16 + (lane & 15)) * 64 + kk];
#pragma unroll
            for (int i = 0; i < 2; ++i)
#pragma unroll
                for (int j = 0; j < 4; ++j)
                    acc[i][j] = __builtin_amdgcn_mfma_f32_16x16x32_bf16(a[i], b[j], acc[i][j], 0, 0, 0);
        }
    }

    if (w == 0) {
#pragma unroll
        for (int i = 0; i < 2; ++i) {
            const int row_base = m0 + wr * 32 + i * 16 + ((lane >> 4) * 4);
#pragma unroll
            for (int j = 0; j < 4; ++j) {
                const int col = nloc + wc * 64 + j * 16 + (lane & 15);
                const float bv_ = bias[col];
#pragma unroll
                for (int r = 0; r < 4; ++r)
                    out[(size_t)(row_base + r) * 512 + col] = f2bf(acc[i][j][r] + bv_);
            }
        }
    } else {
        __syncthreads();
        u16 (*tile)[130] = (u16(*)[130])smem;
#pragma unroll
        for (int i = 0; i < 2; ++i) {
            const int ml = wr * 32 + i * 16 + ((lane >> 4) * 4);
#pragma unroll
            for (int j = 0; j < 4; ++j) {
                const int nl = wc * 64 + j * 16 + (lane & 15);
                const float bv_ = bias[nloc + nl];
#pragma unroll
                for (int r = 0; r < 4; ++r)
                    tile[ml + r][nl] = f2bf(acc[i][j][r] + bv_);
            }
        }
        __syncthreads();
        const int ncol  = tid & 127;
        const int mhalf = tid >> 7;
        const int g = (nb & 3) * 2 + (ncol >> 6);
        const int d = ncol & 63;
        const int c = mb >> 2;
        const int qbase = (mb & 3) * 64 + mhalf * 32;
        u16* dst = out + (size_t)c * CHELEM + d * 2048 + g * 256 + qbase;
#pragma unroll
        for (int v = 0; v < 4; ++v) {
            u16x8 t;
#pragma unroll
            for (int j = 0; j < 8; ++j)
                t[j] = tile[mhalf * 32 + v * 8 + j][ncol];
            *(u16x8*)(dst + v * 8) = t;
        }
    }
}

// ---------------- K23: 256 blocks. Producer phase = R8 k2_pmat (one 16x16 P
// subtile per block, c=bid&15 -> chunk per XCD). Hand-off: RELAXED spin (no
// per-poll cache invalidate -- R9 lesson) + single ACQUIRE. Consumer phase =
// R8 k3 rebalanced to 256 blocks (16 rows x 512 cols each). ----------------
__global__ __launch_bounds__(256) void k23_pv(
        const u16* __restrict__ Kt2, const u16* __restrict__ Vt2,
        const u16* __restrict__ Qb, u16* __restrict__ Pb,
        int* __restrict__ flag, float* __restrict__ outp) {
    __shared__ float red[4][16][16];
    const int tid = threadIdx.x;
    const int lane = tid & 63, w = tid >> 6;
    const int bid = blockIdx.x;

    // ---- produce one 16x16 subtile of P_c (R8-verified body) ----
    {
        const int c   = bid & 15;
        const int sub = bid >> 4;
        const int dq = sub >> 2, eq = sub & 3;
        const u16* Vc = Vt2 + (size_t)c * CHELEM;
        const u16* Kc = Kt2 + (size_t)c * CHELEM;
        const int krow = lane & 15;
        const int arow = (dq * 16 + krow) * 2048;
        const int brow = (eq * 16 + krow) * 2048;
        const int kb = w * 512 + (lane >> 4) * 8;

        f32x4 acc = {};
#pragma unroll
        for (int kt = 0; kt < 16; ++kt) {
            const int k0 = kb + kt * 32;
            bh8 a = *(const bh8*)&Vc[arow + k0];
            bh8 b = *(const bh8*)&Kc[brow + k0];
            acc = __builtin_amdgcn_mfma_f32_16x16x32_bf16(a, b, acc, 0, 0, 0);
        }
#pragma unroll
        for (int r = 0; r < 4; ++r)
            red[w][(lane >> 4) * 4 + r][lane & 15] = acc[r];
        __syncthreads();                        // drains vmcnt for all waves
        const int row = tid >> 4, col = tid & 15;
        float s = red[0][row][col] + red[1][row][col] + red[2][row][col] + red[3][row][col];
        Pb[c * 4096 + (dq * 16 + row) * 64 + eq * 16 + col] = f2bf(s * 0.125f);
        __syncthreads();                        // all Pb stores issued+drained
        if (tid == 0)
            __hip_atomic_fetch_add(flag, 1, __ATOMIC_RELEASE, __HIP_MEMORY_SCOPE_AGENT);
    }

    // ---- wait for all 256 P subtiles: RELAXED poll, ONE acquire at exit ----
    if (tid == 0) {
        int it = 0;
        while (__hip_atomic_load(flag, __ATOMIC_RELAXED, __HIP_MEMORY_SCOPE_AGENT) < 256) {
            __builtin_amdgcn_s_sleep(2);
            if (++it > 200000) break;           // fail loudly (absmax), never hang
        }
        (void)__hip_atomic_load(flag, __ATOMIC_ACQUIRE, __HIP_MEMORY_SCOPE_AGENT);
    }
    __syncthreads();

    // ---- consume: out rows [ib*16, ib*16+16) of batch bb, all 512 cols ----
    const int bb = bid >> 7;
    const int ib = bid & 127;
    const int i0 = ib * 16;
    const int dbase = w * 16;                   // wave owns one 16-wide d-group
    const int krow = lane & 15;
    const int koff = (lane >> 4) * 8;

    f32x4 acc2[8] = {};                         // [head]
#pragma unroll
    for (int h = 0; h < 8; ++h) {
        const int c = h * 2 + bb;
        const u16* Qc = Qb + (size_t)c * CHELEM;
        const u16* Pc = Pb + c * 4096;
#pragma unroll
        for (int ks = 0; ks < 2; ++ks) {
            bh8 a = *(const bh8*)&Qc[(i0 + krow) * 64 + ks * 32 + koff];
            bh8 b = *(const bh8*)&Pc[(dbase + krow) * 64 + ks * 32 + koff];
            acc2[h] = __builtin_amdgcn_mfma_f32_16x16x32_bf16(a, b, acc2[h], 0, 0, 0);
        }
    }
    const int orow_base = bb * 2048 + i0 + (lane >> 4) * 4;
    const int d = dbase + (lane & 15);
#pragma unroll
    for (int r = 0; r < 4; ++r) {
        f32x4 lo = {acc2[0][r], acc2[1][r], acc2[2][r], acc2[3][r]};
        f32x4 hi = {acc2[4][r], acc2[5][r], acc2[6][r], acc2[7][r]};
        float* dst = outp + (size_t)(orow_base + r) * 512 + d * 8;
        *(f32x4*)dst = lo;
        *(f32x4*)(dst + 4) = hi;
    }
}

extern "C" void kernel_launch(void* const* d_in, const int* in_sizes, int n_in,
                              void* d_out, int out_size, void* d_ws, size_t ws_size,
                              hipStream_t stream) {
    const float* x  = (const float*)d_in[0];
    const float* Wq = (const float*)d_in[1];
    const float* bq = (const float*)d_in[2];
    const float* Wk = (const float*)d_in[3];
    const float* bk = (const float*)d_in[4];
    const float* Wv = (const float*)d_in[5];
    const float* bv = (const float*)d_in[6];
    float* outp = (float*)d_out;

    u16* xb = (u16*)d_ws;                 // 4096*512
    u16* Wb = xb + 2097152;               // 3*512*512
    u16* Qb = Wb + 786432;                // 4096*512 (straight)
    u16* Kb = Qb + 2097152;               // Kt2 transposed chunks
    u16* Vb = Kb + 2097152;               // Vt2 transposed chunks
    u16* Pb = Vb + 2097152;               // 16*64*64
    int* flag = (int*)(Pb + 65536);

    k0_convert<<<2816, 256, 0, stream>>>(x, Wq, Wk, Wv, xb, Wb, flag);
    k1_qkv<<<768, 256, 0, stream>>>(xb, Wb, bq, bk, bv, Qb, Kb, Vb);
    k23_pv<<<256, 256, 0, stream>>>(Kb, Vb, Qb, Pb, flag, outp);
}

// Round 11
// 43.139 us; speedup vs baseline: 1.9979x; 1.0782x over previous
//
#include <hip/hip_runtime.h>
#include <stdint.h>

// Problem constants
#define CHELEM 131072        // 2048*64 elements per chunk (flat-reshape chunk)

typedef __attribute__((ext_vector_type(4))) float   f32x4;
typedef __attribute__((ext_vector_type(8))) short   bh8;     // 8 bf16 in 4 VGPRs
typedef __attribute__((ext_vector_type(4))) unsigned short u16x4;
typedef __attribute__((ext_vector_type(8))) unsigned short u16x8;
typedef unsigned short u16;

__device__ inline u16 f2bf(float f) {
    union { float f; uint32_t u; } v; v.f = f;
    uint32_t u = v.u;
    u += 0x7FFF + ((u >> 16) & 1);         // RNE
    return (u16)(u >> 16);
}

// ---------------- K1': fused convert + QKV projection GEMM ----------------
// C[m,n] = sum_k x[m,k]*W[n,k] + bias[n]  (gemm_bt), 64x128 tile, 768 blocks.
// Staging: fp32 global -> reg -> cvt bf16 -> LDS (replaces the separate K0
// convert kernel; conversion is redundant across blocks but VALU-cheap).
// Q (w==0): straight [4096][512]. K,V: TRANSPOSED per chunk Kt2[c][d][g][q]
// (c=m>>8, d=f&63, g=f>>6, q=m&255; row r=q*8+g bijection, same perm for K,V).
__global__ __launch_bounds__(256) void k1_qkv(
        const float* __restrict__ x,
        const float* __restrict__ Wq, const float* __restrict__ Wk,
        const float* __restrict__ Wv,
        const float* __restrict__ bq, const float* __restrict__ bk,
        const float* __restrict__ bv,
        u16* __restrict__ Qb, u16* __restrict__ Kb, u16* __restrict__ Vb) {
    __shared__ u16 smem[12288];                 // lA[4096]+lB[8192]; epi tile[64][130] aliases
    u16* lA = smem;
    u16* lB = smem + 4096;
    const int tid  = threadIdx.x;
    const int lane = tid & 63, wid = tid >> 6;
    const int wr = wid >> 1, wc = wid & 1;
    const int swz  = (blockIdx.x & 7) * 96 + (blockIdx.x >> 3);   // XCD swizzle
    const int mb = swz / 12, nb = swz % 12;
    const int w    = nb >> 2;
    const int nloc = (nb & 3) * 128;
    const float4* x4 = (const float4*)x;
    const float4* W4 = (const float4*)((w == 0) ? Wq : ((w == 1) ? Wk : Wv));
    const float*  bias = (w == 0) ? bq : ((w == 1) ? bk : bv);
    u16*          out  = (w == 0) ? Qb : ((w == 1) ? Kb : Vb);
    const int m0 = mb * 64;

    f32x4 acc[2][4] = {};

    for (int kb = 0; kb < 8; ++kb) {
        __syncthreads();
        const int k4 = kb * 16;                 // k0/4
        float4 ra[4], rb[8];
#pragma unroll
        for (int v = 0; v < 4; ++v) {           // A: 64 rows x 16 float4
            const int idx = v * 256 + tid;
            ra[v] = x4[(size_t)(m0 + (idx >> 4)) * 128 + k4 + (idx & 15)];
        }
#pragma unroll
        for (int v = 0; v < 8; ++v) {           // B: 128 rows x 16 float4
            const int idx = v * 256 + tid;
            rb[v] = W4[(size_t)(nloc + (idx >> 4)) * 128 + k4 + (idx & 15)];
        }
#pragma unroll
        for (int v = 0; v < 4; ++v) {
            const int idx = v * 256 + tid;
            u16x4 o;
            o[0] = f2bf(ra[v].x); o[1] = f2bf(ra[v].y);
            o[2] = f2bf(ra[v].z); o[3] = f2bf(ra[v].w);
            *(u16x4*)&lA[(idx >> 4) * 64 + (idx & 15) * 4] = o;
        }
#pragma unroll
        for (int v = 0; v < 8; ++v) {
            const int idx = v * 256 + tid;
            u16x4 o;
            o[0] = f2bf(rb[v].x); o[1] = f2bf(rb[v].y);
            o[2] = f2bf(rb[v].z); o[3] = f2bf(rb[v].w);
            *(u16x4*)&lB[(idx >> 4) * 64 + (idx & 15) * 4] = o;
        }
        __syncthreads();
#pragma unroll
        for (int ks = 0; ks < 2; ++ks) {
            const int kk = ks * 32 + (lane >> 4) * 8;
            bh8 a[2], b[4];
#pragma unroll
            for (int i = 0; i < 2; ++i)
                a[i] = *(const bh8*)&lA[(wr * 32 + i * 16 + (lane & 15)) * 64 + kk];
#pragma unroll
            for (int j = 0; j < 4; ++j)
                b[j] = *(const bh8*)&lB[(wc * 64 + j * 16 + (lane & 15)) * 64 + kk];
#pragma unroll
            for (int i = 0; i < 2; ++i)
#pragma unroll
                for (int j = 0; j < 4; ++j)
                    acc[i][j] = __builtin_amdgcn_mfma_f32_16x16x32_bf16(a[i], b[j], acc[i][j], 0, 0, 0);
        }
    }

    if (w == 0) {
        // straight store (Q)
#pragma unroll
        for (int i = 0; i < 2; ++i) {
            const int row_base = m0 + wr * 32 + i * 16 + ((lane >> 4) * 4);
#pragma unroll
            for (int j = 0; j < 4; ++j) {
                const int col = nloc + wc * 64 + j * 16 + (lane & 15);
                const float bv_ = bias[col];
#pragma unroll
                for (int r = 0; r < 4; ++r)
                    out[(size_t)(row_base + r) * 512 + col] = f2bf(acc[i][j][r] + bv_);
            }
        }
    } else {
        // transposed store (K,V): stage to padded LDS tile, scatter to Kt2[c][d][g][q]
        __syncthreads();
        u16 (*tile)[130] = (u16(*)[130])smem;
#pragma unroll
        for (int i = 0; i < 2; ++i) {
            const int ml = wr * 32 + i * 16 + ((lane >> 4) * 4);
#pragma unroll
            for (int j = 0; j < 4; ++j) {
                const int nl = wc * 64 + j * 16 + (lane & 15);
                const float bv_ = bias[nloc + nl];
#pragma unroll
                for (int r = 0; r < 4; ++r)
                    tile[ml + r][nl] = f2bf(acc[i][j][r] + bv_);
            }
        }
        __syncthreads();
        const int ncol  = tid & 127;
        const int mhalf = tid >> 7;
        const int g = (nb & 3) * 2 + (ncol >> 6);
        const int d = ncol & 63;
        const int c = mb >> 2;
        const int qbase = (mb & 3) * 64 + mhalf * 32;
        u16* dst = out + (size_t)c * CHELEM + d * 2048 + g * 256 + qbase;
#pragma unroll
        for (int v = 0; v < 4; ++v) {
            u16x8 t;
#pragma unroll
            for (int j = 0; j < 8; ++j)
                t[j] = tile[mhalf * 32 + v * 8 + j][ncol];
            *(u16x8*)(dst + v * 8) = t;
        }
    }
}

// ---------------- K2: Pb[c][d][e] = scale * sum_k Vt2[c][d][k] * Kt2[c][e][k] ----------------
// (verbatim R8 winner) 256 blocks: c = bid%16, sub = bid/16 -> 16x16 (d,e)
// subtile. 4 waves split K=2048; frags direct from global; LDS reduce.
__global__ __launch_bounds__(256) void k2_pmat(
        const u16* __restrict__ Kt2, const u16* __restrict__ Vt2,
        u16* __restrict__ Pb) {
    __shared__ float red[4][16][16];
    const int tid = threadIdx.x;
    const int lane = tid & 63, w = tid >> 6;
    const int c   = blockIdx.x & 15;
    const int sub = blockIdx.x >> 4;
    const int dq = sub >> 2, eq = sub & 3;
    const u16* Vc = Vt2 + (size_t)c * CHELEM;
    const u16* Kc = Kt2 + (size_t)c * CHELEM;
    const int krow = lane & 15;
    const int arow = (dq * 16 + krow) * 2048;
    const int brow = (eq * 16 + krow) * 2048;
    const int kb = w * 512 + (lane >> 4) * 8;

    f32x4 acc = {};
#pragma unroll
    for (int kt = 0; kt < 16; ++kt) {
        const int k0 = kb + kt * 32;
        bh8 a = *(const bh8*)&Vc[arow + k0];
        bh8 b = *(const bh8*)&Kc[brow + k0];
        acc = __builtin_amdgcn_mfma_f32_16x16x32_bf16(a, b, acc, 0, 0, 0);
    }
#pragma unroll
    for (int r = 0; r < 4; ++r)
        red[w][(lane >> 4) * 4 + r][lane & 15] = acc[r];
    __syncthreads();
    const int row = tid >> 4, col = tid & 15;
    float s = red[0][row][col] + red[1][row][col] + red[2][row][col] + red[3][row][col];
    Pb[c * 4096 + (dq * 16 + row) * 64 + eq * 16 + col] = f2bf(s * 0.125f);  // scale = DIM^-0.5
}

// ---------------- K3: out_c = Q_c @ P_c^T  (K=64 per head, no LDS; verbatim R8) ----------------
__global__ __launch_bounds__(256) void k3_out(
        const u16* __restrict__ Qb, const u16* __restrict__ Pb,
        float* __restrict__ outp) {
    const int tid = threadIdx.x;
    const int lane = tid & 63, w = tid >> 6;
    const int bb = blockIdx.x >> 6;          // 128 blocks: 64 row-blocks per bb
    const int ib = blockIdx.x & 63;
    const int i0 = ib * 32 + (w >> 1) * 16;
    const int dbase = (w & 1) * 32;
    const int krow = lane & 15;
    const int koff = (lane >> 4) * 8;

    f32x4 acc[8][2] = {};                    // [head][nf]
#pragma unroll
    for (int h = 0; h < 8; ++h) {
        const int c = h * 2 + bb;
        const u16* Qc = Qb + (size_t)c * CHELEM;
        const u16* Pc = Pb + c * 4096;
#pragma unroll
        for (int ks = 0; ks < 2; ++ks) {
            bh8 a = *(const bh8*)&Qc[(i0 + krow) * 64 + ks * 32 + koff];
#pragma unroll
            for (int nf = 0; nf < 2; ++nf) {
                bh8 b = *(const bh8*)&Pc[(dbase + nf * 16 + krow) * 64 + ks * 32 + koff];
                acc[h][nf] = __builtin_amdgcn_mfma_f32_16x16x32_bf16(a, b, acc[h][nf], 0, 0, 0);
            }
        }
    }
    const int orow_base = bb * 2048 + ib * 32 + (w >> 1) * 16 + (lane >> 4) * 4;
#pragma unroll
    for (int nf = 0; nf < 2; ++nf) {
        const int d = dbase + nf * 16 + (lane & 15);
#pragma unroll
        for (int r = 0; r < 4; ++r) {
            f32x4 lo = {acc[0][nf][r], acc[1][nf][r], acc[2][nf][r], acc[3][nf][r]};
            f32x4 hi = {acc[4][nf][r], acc[5][nf][r], acc[6][nf][r], acc[7][nf][r]};
            float* dst = outp + (size_t)(orow_base + r) * 512 + d * 8;
            *(f32x4*)dst = lo;
            *(f32x4*)(dst + 4) = hi;
        }
    }
}

extern "C" void kernel_launch(void* const* d_in, const int* in_sizes, int n_in,
                              void* d_out, int out_size, void* d_ws, size_t ws_size,
                              hipStream_t stream) {
    const float* x  = (const float*)d_in[0];
    const float* Wq = (const float*)d_in[1];
    const float* bq = (const float*)d_in[2];
    const float* Wk = (const float*)d_in[3];
    const float* bk = (const float*)d_in[4];
    const float* Wv = (const float*)d_in[5];
    const float* bv = (const float*)d_in[6];
    float* outp = (float*)d_out;

    u16* Qb = (u16*)d_ws;                 // 4096*512 (straight)
    u16* Kb = Qb + 2097152;               // Kt2 transposed chunks
    u16* Vb = Kb + 2097152;               // Vt2 transposed chunks
    u16* Pb = Vb + 2097152;               // 16*64*64

    k1_qkv<<<768, 256, 0, stream>>>(x, Wq, Wk, Wv, bq, bk, bv, Qb, Kb, Vb);
    k2_pmat<<<256, 256, 0, stream>>>(Kb, Vb, Pb);
    k3_out<<<128, 256, 0, stream>>>(Qb, Pb, outp);
}